// Round 1
// 580.644 us; speedup vs baseline: 3.5534x; 3.5534x over previous
//
#include <hip/hip_runtime.h>
#include <cstddef>

// SPDRectified: out = U clamp(S, eps) U^T for 16384 symmetric 64x64 fp32 matrices.
// Matrix-sign Newton-Schulz: out = (X + X*sign(X))/2, Y0 = X/||X||_F,
// 4 quintic + 3 cubic iterations (same schedule as the verified fp32 kernel).
//
// This version runs all 19 matmuls on the bf16 matrix cores with a 2-word
// hi/lo error-compensated split (Ahi*Bhi + Ahi*Blo + Alo*Bhi, fp32 accum)
// => ~2^-17 relative matmul error, numerically equivalent to the fp32 path.
// All operands are symmetric (polynomials of one X), so A- and B-fragments
// use the identical LDS read pattern and C-tiles are stored transposed;
// any MFMA layout-transpose convention error cancels by symmetry.
//
// LDS layout: elem(i,j) = i*64 + (j ^ ((i&7)<<3))  -- XOR swizzle, verified
// conflict-free (bank-floor) for frag ds_read_b128, tile ds_write_b64,
// init writes, and the final transposed Y0 tile read.

#define QA 3.4445f
#define QB (-4.7750f)
#define QC 2.0315f

using bf16x8 = __attribute__((ext_vector_type(8))) __bf16;
using f32x16 = __attribute__((ext_vector_type(16))) float;
using u32x4  = __attribute__((ext_vector_type(4))) unsigned int;
using u16x4  = __attribute__((ext_vector_type(4))) unsigned short;

__device__ __forceinline__ unsigned short f2bf(float f) {   // RNE truncate
    unsigned u = __float_as_uint(f);
    u += 0x7FFFu + ((u >> 16) & 1u);
    return (unsigned short)(u >> 16);
}
__device__ __forceinline__ float bf2f(unsigned short h) {
    return __uint_as_float(((unsigned)h) << 16);
}

__device__ __forceinline__ bf16x8 ld8(const unsigned short* p) {
    return __builtin_bit_cast(bf16x8, *reinterpret_cast<const u32x4*>(p));
}

struct Frags { bf16x8 h[4]; bf16x8 l[4]; };

// Load A- (or, by symmetry, B-) fragments for a 32-row band: row = rowbase+(lane&31),
// k = 16*s + 8*(lane>>5) + [0..8). One ds_read_b128 per fragment, swizzled.
__device__ __forceinline__ void load_frags(Frags& f, const unsigned short* bh,
                                           const unsigned short* bl,
                                           int rowbase, int lane) {
    const int r   = rowbase + (lane & 31);
    const int kb  = (lane >> 5) << 3;
    const int swz = (r & 7) << 3;
    const unsigned short* ph = bh + r * 64;
    const unsigned short* pl = bl + r * 64;
#pragma unroll
    for (int s = 0; s < 4; ++s) {
        const int e = (kb + 16 * s) ^ swz;
        f.h[s] = ld8(ph + e);
        f.l[s] = ld8(pl + e);
    }
}

// 3-term compensated product: acc = Ah*Bh + Ah*Bl + Al*Bh  (fp32 accum).
__device__ __forceinline__ f32x16 mm12(const Frags& A, const Frags& B) {
    f32x16 acc = {};
#pragma unroll
    for (int s = 0; s < 4; ++s)
        acc = __builtin_amdgcn_mfma_f32_32x32x16_bf16(A.h[s], B.h[s], acc, 0, 0, 0);
#pragma unroll
    for (int s = 0; s < 4; ++s)
        acc = __builtin_amdgcn_mfma_f32_32x32x16_bf16(A.h[s], B.l[s], acc, 0, 0, 0);
#pragma unroll
    for (int s = 0; s < 4; ++s)
        acc = __builtin_amdgcn_mfma_f32_32x32x16_bf16(A.l[s], B.h[s], acc, 0, 0, 0);
    return acc;
}

// C layout (m74/m101): col = lane&31, row = (reg&3) + 8*(reg>>2) + 4*(lane>>5).
// 4 consecutive regs = 4 consecutive rows, same col -> store transposed
// (buf[col][rows]) as packed u16x4 = ds_write_b64. Symmetry makes it exact.
__device__ __forceinline__ void store_tile(unsigned short* bh, unsigned short* bl,
                                           const f32x16& c, int wr, int wc, int lane) {
    const int col = 32 * wc + (lane & 31);
    const int swz = (col & 7) << 3;
    unsigned short* ph = bh + col * 64;
    unsigned short* pl = bl + col * 64;
    const int rb0 = 32 * wr + ((lane >> 5) << 2);
#pragma unroll
    for (int g = 0; g < 4; ++g) {
        const int rb = rb0 + 8 * g;
        u16x4 hv, lv;
#pragma unroll
        for (int j = 0; j < 4; ++j) {
            const float x = c[4 * g + j];
            const unsigned short h = f2bf(x);
            hv[j] = h;
            lv[j] = f2bf(x - bf2f(h));
        }
        const int e = rb ^ swz;
        *reinterpret_cast<u16x4*>(ph + e) = hv;
        *reinterpret_cast<u16x4*>(pl + e) = lv;
    }
}

__global__ __launch_bounds__(256, 3)
void spd_rectified_kernel(const float* __restrict__ Xg_all,
                          float* __restrict__ out_all) {
    // 6 bf16 64x64 buffers = 48 KB -> 3 blocks/CU.
    __shared__ u32x4 smem[6 * 512];
    __shared__ float red[4];
    unsigned short* const Y0h = reinterpret_cast<unsigned short*>(smem);
    unsigned short* const Y0l = Y0h + 4096;
    unsigned short* const Yh  = Y0h + 8192;
    unsigned short* const Yl  = Y0h + 12288;
    unsigned short* const Zh  = Y0h + 16384;
    unsigned short* const Zl  = Y0h + 20480;

    const int tid  = threadIdx.x;
    const int lane = tid & 63;
    const int w    = tid >> 6;
    const int wr   = w >> 1;      // wave's 32-row band of C
    const int wc   = w & 1;       // wave's 32-col band of C
    const int cl   = lane & 31;
    const int hh   = (lane >> 5) << 2;

    const float* __restrict__ Xg = Xg_all + (size_t)blockIdx.x * 4096;
    float* __restrict__ Og = out_all + (size_t)blockIdx.x * 4096;

    // ---- load X, Frobenius^2 reduction ----
    float4 v[4];
    float ss = 0.f;
#pragma unroll
    for (int q = 0; q < 4; ++q) {
        v[q] = reinterpret_cast<const float4*>(Xg)[q * 256 + tid];
        ss += v[q].x * v[q].x + v[q].y * v[q].y + v[q].z * v[q].z + v[q].w * v[q].w;
    }
#pragma unroll
    for (int off = 32; off > 0; off >>= 1) ss += __shfl_down(ss, off, 64);
    if (lane == 0) red[w] = ss;
    __syncthreads();
    const float total = red[0] + red[1] + red[2] + red[3];
    const float ainv  = rsqrtf(total + 1e-30f);
    const float alpha = total * ainv;          // sqrt(total)

    // ---- Y0 = X * ainv, split to bf16 hi/lo, swizzled write ----
#pragma unroll
    for (int q = 0; q < 4; ++q) {
        const int idx = q * 256 + tid;
        const int r   = idx >> 4;
        const int c0  = (idx & 15) << 2;
        const int e   = r * 64 + (c0 ^ ((r & 7) << 3));
        const float xs[4] = {v[q].x * ainv, v[q].y * ainv, v[q].z * ainv, v[q].w * ainv};
        u16x4 hv, lv;
#pragma unroll
        for (int j = 0; j < 4; ++j) {
            const unsigned short h = f2bf(xs[j]);
            hv[j] = h;
            lv[j] = f2bf(xs[j] - bf2f(h));
        }
        *reinterpret_cast<u16x4*>(Y0h + e) = hv;
        *reinterpret_cast<u16x4*>(Y0l + e) = lv;
    }
    __syncthreads();

    const unsigned short* srch = Y0h;
    const unsigned short* srcl = Y0l;
    Frags A, B;

    // ---- 4 quintic iterations: Y <- Y*(QA*I + QB*Y^2 + QC*Y^4) ----
    for (int it = 0; it < 4; ++it) {
        load_frags(A, srch, srcl, 32 * wr, lane);        // Y rows (kept for mm3)
        load_frags(B, srch, srcl, 32 * wc, lane);        // Y "cols" (symmetric)
        const f32x16 z = mm12(A, B);                     // Z = Y^2
        store_tile(Zh, Zl, z, wr, wc, lane);             // prev Z readers done at prior barrier
        __syncthreads();
        Frags A2, B2;
        load_frags(A2, Zh, Zl, 32 * wr, lane);
        load_frags(B2, Zh, Zl, 32 * wc, lane);
        const f32x16 t = mm12(A2, B2);                   // T = Z^2
        f32x16 wv;
#pragma unroll
        for (int r = 0; r < 16; ++r) {                   // W = QA*I + QB*Z + QC*T
            float val = QB * z[r] + QC * t[r];
            if (wr == wc && (((r >> 2) << 3) + (r & 3) + hh) == cl) val += QA;
            wv[r] = val;
        }
        __syncthreads();                                 // all Z reads complete
        store_tile(Zh, Zl, wv, wr, wc, lane);            // W overwrites Z buffers
        __syncthreads();
        load_frags(B, Zh, Zl, 32 * wc, lane);            // W frags; A still holds Y
        const f32x16 yn = mm12(A, B);                    // Ynew = Y*W
        store_tile(Yh, Yl, yn, wr, wc, lane);            // Y reads all pre-barrier-1
        __syncthreads();
        srch = Yh; srcl = Yl;
    }

    // ---- 3 cubic Newton-Schulz: Y <- Y*(1.5I - 0.5*Y^2) ----
    for (int it = 0; it < 3; ++it) {
        load_frags(A, srch, srcl, 32 * wr, lane);
        load_frags(B, srch, srcl, 32 * wc, lane);
        const f32x16 z = mm12(A, B);                     // Z = Y^2
        f32x16 wv;
#pragma unroll
        for (int r = 0; r < 16; ++r) {                   // W = 1.5I - 0.5Z
            float val = -0.5f * z[r];
            if (wr == wc && (((r >> 2) << 3) + (r & 3) + hh) == cl) val += 1.5f;
            wv[r] = val;
        }
        store_tile(Zh, Zl, wv, wr, wc, lane);            // prev W readers done at prior barrier
        __syncthreads();
        load_frags(B, Zh, Zl, 32 * wc, lane);
        const f32x16 yn = mm12(A, B);                    // Ynew = Y*W
        store_tile(Yh, Yl, yn, wr, wc, lane);            // Y reads all pre-barrier above
        __syncthreads();
    }

    // ---- final: out = 0.5*alpha*(Y0 + Y0*S), S = Y ----
    load_frags(A, Y0h, Y0l, 32 * wr, lane);
    load_frags(B, srch, srcl, 32 * wc, lane);
    const f32x16 c = mm12(A, B);
    const float hsc = 0.5f * alpha;
    const int col = 32 * wc + cl;
    const int swz = (col & 7) << 3;
    const int rb0 = 32 * wr + hh;
#pragma unroll
    for (int g = 0; g < 4; ++g) {
        const int rb = rb0 + 8 * g;
        const int e  = col * 64 + ((rb) ^ swz);
        const u16x4 yh = *reinterpret_cast<const u16x4*>(Y0h + e);
        const u16x4 yl = *reinterpret_cast<const u16x4*>(Y0l + e);
#pragma unroll
        for (int j = 0; j < 4; ++j) {
            const float y0 = bf2f(yh[j]) + bf2f(yl[j]);
            Og[(rb + j) * 64 + col] = hsc * (y0 + c[4 * g + j]);
        }
    }
}

extern "C" void kernel_launch(void* const* d_in, const int* in_sizes, int n_in,
                              void* d_out, int out_size, void* d_ws, size_t ws_size,
                              hipStream_t stream) {
    const float* x = (const float*)d_in[0];
    float* out = (float*)d_out;
    const int nmat = in_sizes[0] >> 12;   // same convention as the verified kernel
    spd_rectified_kernel<<<nmat, 256, 0, stream>>>(x, out);
}